// Round 11
// baseline (2060.945 us; speedup 1.0000x reference)
//
#include <hip/hip_runtime.h>
#include <stdint.h>

#define T_LEN    1048576
#define TY_LEN   1048561
#define OUT_W    1048562
#define NM       32
#define WIN      16
#define NCH      4096
#define CL       256
#define CBT      192    // conv block threads = outputs per block
#define XS_W     208    // 192 + 15 halo + pad; 32*208*4 = 26624 B
#define NF4      52     // XS_W/4 float4s per channel

typedef float f4 __attribute__((ext_vector_type(4)));

__device__ inline float sgnf(float a){
    return (a > 0.0f) ? 1.0f : ((a < 0.0f) ? -1.0f : 0.0f);
}

// ---------------- transpose w[o][i][h] -> wT[h][i][o] (o fastest)
__global__ void wtrans_kernel(const float* __restrict__ w, float* __restrict__ wT){
    const int idx = blockIdx.x * 256 + threadIdx.x;
    if (idx >= NM * NM * WIN) return;
    const int o = idx / (NM * WIN);
    const int r = idx - o * (NM * WIN);
    const int i = r / WIN;
    const int h = r - i * WIN;
    wT[(h * NM + i) * NM + o] = w[idx];
}

// Weight delivery via VMEM (vmcnt) instead of SMEM (lgkmcnt): counted
// s_waitcnt vmcnt(8) keeps a depth-2 pipeline of 8x dwordx4 loads in flight,
// decoupled from the xv ds_reads (lgkm, in-order). Explicit "+v"/"v" operand
// deps make the waits airtight against reordering.
#define WLD(dst, p, OFFSTR) \
    asm volatile("global_load_dwordx4 %0, %1, off offset:" OFFSTR \
                 : "=v"(dst) : "v"(p))

#define LOADW(B, I) { const float* _p = wp + (I) * NM; \
    WLD(B[0], _p, "0");  WLD(B[1], _p, "16"); WLD(B[2], _p, "32"); \
    WLD(B[3], _p, "48"); WLD(B[4], _p, "64"); WLD(B[5], _p, "80"); \
    WLD(B[6], _p, "96"); WLD(B[7], _p, "112"); }

#define WAIT8(A, B) asm volatile("s_waitcnt vmcnt(8)" \
    : "+v"(A[0]),"+v"(A[1]),"+v"(A[2]),"+v"(A[3]), \
      "+v"(A[4]),"+v"(A[5]),"+v"(A[6]),"+v"(A[7]) \
    : "v"(B[0]),"v"(B[1]),"v"(B[2]),"v"(B[3]), \
      "v"(B[4]),"v"(B[5]),"v"(B[6]),"v"(B[7]))

#define WAIT0(A) asm volatile("s_waitcnt vmcnt(0)" \
    : "+v"(A[0]),"+v"(A[1]),"+v"(A[2]),"+v"(A[3]), \
      "+v"(A[4]),"+v"(A[5]),"+v"(A[6]),"+v"(A[7]))

#define FQ(V, q) \
    acc[4*(q)+0] = fmaf((V).x, xv, acc[4*(q)+0]); \
    acc[4*(q)+1] = fmaf((V).y, xv, acc[4*(q)+1]); \
    acc[4*(q)+2] = fmaf((V).z, xv, acc[4*(q)+2]); \
    acc[4*(q)+3] = fmaf((V).w, xv, acc[4*(q)+3])

#define FMAS(A, I) { const float xv = xs[(I) * XS_W + tl + h]; \
    FQ(A[0],0); FQ(A[1],1); FQ(A[2],2); FQ(A[3],3); \
    FQ(A[4],4); FQ(A[5],5); FQ(A[6],6); FQ(A[7],7); }

#define STEP2(I) \
    LOADW(WB, (I)+1); WAIT8(WA, WB); FMAS(WA, (I)); \
    LOADW(WA, (I)+2); WAIT8(WB, WA); FMAS(WB, (I)+1);

// ---------------- conv, XLA-CPU-faithful order (h-major, i-minor, bias last):
// per output (o,t): acc = 0; for h: for i: acc = fmaf(w[o][i][h], x[i][t+h], acc)
// FMA chain per accumulator is operand-identical to the passing kernels.
__global__ __launch_bounds__(192, 3) void conv_kernel(
    const float* __restrict__ x, const float* __restrict__ wT,
    const float* __restrict__ b, float* __restrict__ out)
{
    __shared__ float xs[NM * XS_W];
    const int base = blockIdx.x * CBT;
    for (int idx = threadIdx.x; idx < NM * NF4; idx += CBT) {
        const int i = idx / NF4;
        const int q = idx - i * NF4;
        const int t0 = base + q * 4;
        float4 v;
        if (t0 + 3 < T_LEN) {
            v = *reinterpret_cast<const float4*>(x + (size_t)i * T_LEN + t0);
        } else {
            v.x = (t0 + 0 < T_LEN) ? x[(size_t)i * T_LEN + t0 + 0] : 0.0f;
            v.y = (t0 + 1 < T_LEN) ? x[(size_t)i * T_LEN + t0 + 1] : 0.0f;
            v.z = (t0 + 2 < T_LEN) ? x[(size_t)i * T_LEN + t0 + 2] : 0.0f;
            v.w = (t0 + 3 < T_LEN) ? x[(size_t)i * T_LEN + t0 + 3] : 0.0f;
        }
        *reinterpret_cast<float4*>(&xs[i * XS_W + q * 4]) = v;
    }
    __syncthreads();
    asm volatile("s_waitcnt vmcnt(0)" ::: "memory");   // clean slate for counting
    const int tl = threadIdx.x;
    float acc[NM];
#pragma unroll
    for (int o = 0; o < NM; ++o) acc[o] = 0.0f;
    f4 WA[8], WB[8];
#pragma unroll 1
    for (int h = 0; h < WIN; ++h) {
        const float* wp = wT + h * NM * NM;
        LOADW(WA, 0);
        STEP2(0)  STEP2(2)  STEP2(4)  STEP2(6)
        STEP2(8)  STEP2(10) STEP2(12) STEP2(14)
        STEP2(16) STEP2(18) STEP2(20) STEP2(22)
        STEP2(24) STEP2(26) STEP2(28)
        LOADW(WB, 31); WAIT8(WA, WB); FMAS(WA, 30);
        WAIT0(WB); FMAS(WB, 31);
    }
    const int t = base + tl;
    if (t < TY_LEN) {
#pragma unroll
        for (int o = 0; o < NM; ++o)
            out[(size_t)o * OUT_W + 1 + t] = acc[o] + b[o];
    }
}

// ---------------- pass A: per-(market, chunk) 4-candidate transition map
__global__ __launch_bounds__(256) void scan_pass_a(
    const float* __restrict__ yb, const float* __restrict__ sp,
    const float* __restrict__ pwv, uint32_t* __restrict__ trans)
{
    const int gid = blockIdx.x * 256 + threadIdx.x;
    const int m = gid >> 12;
    const int c = gid & (NCH - 1);
    const float pw = pwv[m];
    float p0 = -1.0f, p1 = 0.0f, p2 = 1.0f, p3 = sp[m];
    const float* hr = yb + (size_t)m * OUT_W + 1 + c * CL;
    const int limit0 = TY_LEN - c * CL;
    const int limit = limit0 < CL ? limit0 : CL;
    int j = 0;
    for (; j + 4 <= limit; j += 4) {
        const float4 h = *reinterpret_cast<const float4*>(hr + j);
#define STEPA(hv) { const float hv_ = (hv); \
        p0 = sgnf(fmaf(p0, pw, hv_)); \
        p1 = sgnf(fmaf(p1, pw, hv_)); \
        p2 = sgnf(fmaf(p2, pw, hv_)); \
        p3 = sgnf(fmaf(p3, pw, hv_)); }
        STEPA(h.x); STEPA(h.y); STEPA(h.z); STEPA(h.w);
    }
    for (; j < limit; ++j) { STEPA(hr[j]); }
#undef STEPA
    const uint32_t e0 = (uint32_t)((int)p0 + 1);
    const uint32_t e1 = (uint32_t)((int)p1 + 1);
    const uint32_t e2 = (uint32_t)((int)p2 + 1);
    const uint32_t e3 = (uint32_t)((int)p3 + 1);
    trans[m * NCH + c] = e0 | (e1 << 8) | (e2 << 16) | (e3 << 24);
}

// ---------------- pass B: compose maps per market, emit entry state per chunk
__device__ inline uint32_t map_comp(uint32_t f, uint32_t g){
    uint32_t r = 0;
#pragma unroll
    for (int k = 0; k < 4; ++k) {
        const uint32_t s = (g >> (8 * k)) & 0xFFu;
        const uint32_t o = (f >> (8 * s)) & 0xFFu;
        r |= o << (8 * k);
    }
    return r;
}

__global__ __launch_bounds__(256) void scan_pass_b(
    const uint32_t* __restrict__ trans, uint8_t* __restrict__ entries)
{
    const uint32_t ID = 0x03020100u;   // identity; state 3 = raw start_pos
    const int m = blockIdx.x;
    const int tid = threadIdx.x;
    __shared__ uint32_t S[256];
    uint32_t maps[16];
    uint32_t seg = ID;
    const uint32_t* tr = trans + m * NCH + tid * 16;
#pragma unroll
    for (int j = 0; j < 16; ++j) { maps[j] = tr[j]; seg = map_comp(maps[j], seg); }
    S[tid] = seg;
    __syncthreads();
    for (int off = 1; off < 256; off <<= 1) {
        const uint32_t v = (tid >= off) ? S[tid - off] : ID;
        __syncthreads();
        if (tid >= off) S[tid] = map_comp(S[tid], v);
        __syncthreads();
    }
    const uint32_t pre = (tid == 0) ? ID : S[tid - 1];
    uint32_t s = (pre >> 24) & 0xFFu;   // prefix applied to initial state 3
    uint8_t* er = entries + m * NCH + tid * 16;
#pragma unroll
    for (int j = 0; j < 16; ++j) {
        er[j] = (uint8_t)s;
        s = (maps[j] >> (8 * s)) & 0xFFu;
    }
}

// ---------------- pass C: re-scan with known entry state; in-place y -> tanh
__global__ __launch_bounds__(256) void scan_pass_c(
    float* yo, const float* __restrict__ sp, const float* __restrict__ pwv,
    const uint8_t* __restrict__ entries)
{
    const int gid = blockIdx.x * 256 + threadIdx.x;
    const int m = gid >> 12;
    const int c = gid & (NCH - 1);
    const float pw = pwv[m];
    const float spv = sp[m];
    const uint32_t s = entries[m * NCH + c];
    float p = (s == 3u) ? spv : ((float)(int)s - 1.0f);
    float* row = yo + (size_t)m * OUT_W + 1 + c * CL;
    if (c == 0) yo[(size_t)m * OUT_W] = spv;
    const int limit0 = TY_LEN - c * CL;
    const int limit = limit0 < CL ? limit0 : CL;
    int j = 0;
    for (; j + 4 <= limit; j += 4) {
        const float4 h = *reinterpret_cast<const float4*>(row + j);
        float a;
        a = fmaf(p, pw, h.x); row[j+0] = tanhf(a); p = sgnf(a);
        a = fmaf(p, pw, h.y); row[j+1] = tanhf(a); p = sgnf(a);
        a = fmaf(p, pw, h.z); row[j+2] = tanhf(a); p = sgnf(a);
        a = fmaf(p, pw, h.w); row[j+3] = tanhf(a); p = sgnf(a);
    }
    for (; j < limit; ++j) {
        const float a = fmaf(p, pw, row[j]);
        row[j] = tanhf(a);
        p = sgnf(a);
    }
}

extern "C" void kernel_launch(void* const* d_in, const int* in_sizes, int n_in,
                              void* d_out, int out_size, void* d_ws, size_t ws_size,
                              hipStream_t stream)
{
    const float* x   = (const float*)d_in[0];
    const float* spv = (const float*)d_in[1];
    const float* w   = (const float*)d_in[2];
    const float* b   = (const float*)d_in[3];
    const float* pw  = (const float*)d_in[4];
    float* out = (float*)d_out;

    // workspace: wT 64 KiB | trans 512 KiB | entries 128 KiB
    uint8_t* ws = (uint8_t*)d_ws;
    float*    wT      = (float*)ws;
    uint32_t* trans   = (uint32_t*)(ws + 65536);
    uint8_t*  entries = (uint8_t*)(ws + 65536 + 524288);

    const int conv_blocks = (TY_LEN + CBT - 1) / CBT;   // 5461
    wtrans_kernel<<<64, 256, 0, stream>>>(w, wT);
    conv_kernel<<<conv_blocks, CBT, 0, stream>>>(x, wT, b, out);
    scan_pass_a<<<(NM * NCH) / 256, 256, 0, stream>>>(out, spv, pw, trans);
    scan_pass_b<<<NM, 256, 0, stream>>>(trans, entries);
    scan_pass_c<<<(NM * NCH) / 256, 256, 0, stream>>>(out, spv, pw, entries);
}

// Round 12
// 522.813 us; speedup vs baseline: 3.9420x; 3.9420x over previous
//
#include <hip/hip_runtime.h>
#include <stdint.h>

#define T_LEN    1048576
#define TY_LEN   1048561
#define OUT_W    1048562
#define NM       32
#define WIN      16
#define NCH      4096
#define CL       256
#define CBT      256    // conv block threads (4 waves)
#define TPB      256    // timesteps per block
#define XS_W     272    // 256 + 15 halo + pad; 32*272*4 = 34816 B -> 4 blocks/CU
#define NF4      68     // XS_W/4 float4s per channel

__device__ inline float sgnf(float a){
    return (a > 0.0f) ? 1.0f : ((a < 0.0f) ? -1.0f : 0.0f);
}

// ---------------- weight relayout: w[o][i][h] -> wT2[h][og][i][oi]
// (og = o>>3, oi = o&7). Per (h,og): 32*8 = 256 contiguous floats so a wave's
// weight stream per h is 16 consecutive s_load_dwordx16-able 64B lines.
__global__ void wtrans_kernel(const float* __restrict__ w, float* __restrict__ wT2){
    const int idx = blockIdx.x * 256 + threadIdx.x;
    if (idx >= NM * NM * WIN) return;
    const int o = idx / (NM * WIN);
    const int r = idx - o * (NM * WIN);
    const int i = r / WIN;
    const int h = r - i * WIN;
    wT2[(((h * 4) + (o >> 3)) * NM + i) * 8 + (o & 7)] = w[idx];
}

// ---------------- conv, XLA-CPU-faithful order (h-major, i-minor, bias last):
// per output (o,t): acc = 0; for h: for i: acc = fmaf(w[o][i][h], x[i][t+h], acc)
// Re-tiled: each thread owns 8 o-channels x 4 timesteps (t = base+lane+64*tt).
// Per i-step the wave consumes 32 B of weights for 32 lane-FMAs (4x less
// scalar-load traffic/drains than 32o x 1t). Wave w handles o-group w.
// Per-accumulator FMA chain is operand-identical to the passing kernels.
__global__ __launch_bounds__(256, 4) void conv_kernel(
    const float* __restrict__ x, const float* __restrict__ wT2,
    const float* __restrict__ b, float* __restrict__ out)
{
    __shared__ float xs[NM * XS_W];
    const int base = blockIdx.x * TPB;
    for (int idx = threadIdx.x; idx < NM * NF4; idx += CBT) {
        const int i = idx / NF4;
        const int q = idx - i * NF4;
        const int t0 = base + q * 4;
        float4 v;
        if (t0 + 3 < T_LEN) {
            v = *reinterpret_cast<const float4*>(x + (size_t)i * T_LEN + t0);
        } else {
            v.x = (t0 + 0 < T_LEN) ? x[(size_t)i * T_LEN + t0 + 0] : 0.0f;
            v.y = (t0 + 1 < T_LEN) ? x[(size_t)i * T_LEN + t0 + 1] : 0.0f;
            v.z = (t0 + 2 < T_LEN) ? x[(size_t)i * T_LEN + t0 + 2] : 0.0f;
            v.w = (t0 + 3 < T_LEN) ? x[(size_t)i * T_LEN + t0 + 3] : 0.0f;
        }
        *reinterpret_cast<float4*>(&xs[i * XS_W + q * 4]) = v;
    }
    __syncthreads();
    const int lane = threadIdx.x & 63;
    const int og   = __builtin_amdgcn_readfirstlane(threadIdx.x >> 6);
    float acc[8][4];
#pragma unroll
    for (int oi = 0; oi < 8; ++oi)
#pragma unroll
        for (int tt = 0; tt < 4; ++tt) acc[oi][tt] = 0.0f;
#pragma unroll 1
    for (int h = 0; h < WIN; ++h) {
        const float* wp = wT2 + (size_t)(h * 4 + og) * (NM * 8);  // uniform
#pragma unroll 1
        for (int c = 0; c < 4; ++c) {            // 8-i chunks
            float xv[8][4];
#pragma unroll
            for (int i2 = 0; i2 < 8; ++i2) {
                const int i = c * 8 + i2;
#pragma unroll
                for (int tt = 0; tt < 4; ++tt)
                    xv[i2][tt] = xs[i * XS_W + lane + 64 * tt + h];
            }
#pragma unroll
            for (int i2 = 0; i2 < 8; ++i2) {
                const float* wr = wp + (c * 8 + i2) * 8;   // 32 B, lane-uniform
#pragma unroll
                for (int oi = 0; oi < 8; ++oi) {
                    const float wv = wr[oi];
#pragma unroll
                    for (int tt = 0; tt < 4; ++tt)
                        acc[oi][tt] = fmaf(wv, xv[i2][tt], acc[oi][tt]);
                }
            }
        }
    }
#pragma unroll
    for (int oi = 0; oi < 8; ++oi) {
        const int o = og * 8 + oi;
        const float bv = b[o];
        float* orow = out + (size_t)o * OUT_W + 1 + base + lane;
#pragma unroll
        for (int tt = 0; tt < 4; ++tt) {
            const int t = base + lane + 64 * tt;
            if (t < TY_LEN) orow[64 * tt] = acc[oi][tt] + bv;
        }
    }
}

// ---------------- pass A: per-(market, chunk) 4-candidate transition map
__global__ __launch_bounds__(256) void scan_pass_a(
    const float* __restrict__ yb, const float* __restrict__ sp,
    const float* __restrict__ pwv, uint32_t* __restrict__ trans)
{
    const int gid = blockIdx.x * 256 + threadIdx.x;
    const int m = gid >> 12;
    const int c = gid & (NCH - 1);
    const float pw = pwv[m];
    float p0 = -1.0f, p1 = 0.0f, p2 = 1.0f, p3 = sp[m];
    const float* hr = yb + (size_t)m * OUT_W + 1 + c * CL;
    const int limit0 = TY_LEN - c * CL;
    const int limit = limit0 < CL ? limit0 : CL;
    int j = 0;
    for (; j + 4 <= limit; j += 4) {
        const float4 h = *reinterpret_cast<const float4*>(hr + j);
#define STEPA(hv) { const float hv_ = (hv); \
        p0 = sgnf(fmaf(p0, pw, hv_)); \
        p1 = sgnf(fmaf(p1, pw, hv_)); \
        p2 = sgnf(fmaf(p2, pw, hv_)); \
        p3 = sgnf(fmaf(p3, pw, hv_)); }
        STEPA(h.x); STEPA(h.y); STEPA(h.z); STEPA(h.w);
    }
    for (; j < limit; ++j) { STEPA(hr[j]); }
#undef STEPA
    const uint32_t e0 = (uint32_t)((int)p0 + 1);
    const uint32_t e1 = (uint32_t)((int)p1 + 1);
    const uint32_t e2 = (uint32_t)((int)p2 + 1);
    const uint32_t e3 = (uint32_t)((int)p3 + 1);
    trans[m * NCH + c] = e0 | (e1 << 8) | (e2 << 16) | (e3 << 24);
}

// ---------------- pass B: compose maps per market, emit entry state per chunk
__device__ inline uint32_t map_comp(uint32_t f, uint32_t g){
    uint32_t r = 0;
#pragma unroll
    for (int k = 0; k < 4; ++k) {
        const uint32_t s = (g >> (8 * k)) & 0xFFu;
        const uint32_t o = (f >> (8 * s)) & 0xFFu;
        r |= o << (8 * k);
    }
    return r;
}

__global__ __launch_bounds__(256) void scan_pass_b(
    const uint32_t* __restrict__ trans, uint8_t* __restrict__ entries)
{
    const uint32_t ID = 0x03020100u;   // identity; state 3 = raw start_pos
    const int m = blockIdx.x;
    const int tid = threadIdx.x;
    __shared__ uint32_t S[256];
    uint32_t maps[16];
    uint32_t seg = ID;
    const uint32_t* tr = trans + m * NCH + tid * 16;
#pragma unroll
    for (int j = 0; j < 16; ++j) { maps[j] = tr[j]; seg = map_comp(maps[j], seg); }
    S[tid] = seg;
    __syncthreads();
    for (int off = 1; off < 256; off <<= 1) {
        const uint32_t v = (tid >= off) ? S[tid - off] : ID;
        __syncthreads();
        if (tid >= off) S[tid] = map_comp(S[tid], v);
        __syncthreads();
    }
    const uint32_t pre = (tid == 0) ? ID : S[tid - 1];
    uint32_t s = (pre >> 24) & 0xFFu;   // prefix applied to initial state 3
    uint8_t* er = entries + m * NCH + tid * 16;
#pragma unroll
    for (int j = 0; j < 16; ++j) {
        er[j] = (uint8_t)s;
        s = (maps[j] >> (8 * s)) & 0xFFu;
    }
}

// ---------------- pass C: re-scan with known entry state; in-place y -> tanh
__global__ __launch_bounds__(256) void scan_pass_c(
    float* yo, const float* __restrict__ sp, const float* __restrict__ pwv,
    const uint8_t* __restrict__ entries)
{
    const int gid = blockIdx.x * 256 + threadIdx.x;
    const int m = gid >> 12;
    const int c = gid & (NCH - 1);
    const float pw = pwv[m];
    const float spv = sp[m];
    const uint32_t s = entries[m * NCH + c];
    float p = (s == 3u) ? spv : ((float)(int)s - 1.0f);
    float* row = yo + (size_t)m * OUT_W + 1 + c * CL;
    if (c == 0) yo[(size_t)m * OUT_W] = spv;
    const int limit0 = TY_LEN - c * CL;
    const int limit = limit0 < CL ? limit0 : CL;
    int j = 0;
    for (; j + 4 <= limit; j += 4) {
        const float4 h = *reinterpret_cast<const float4*>(row + j);
        float a;
        a = fmaf(p, pw, h.x); row[j+0] = tanhf(a); p = sgnf(a);
        a = fmaf(p, pw, h.y); row[j+1] = tanhf(a); p = sgnf(a);
        a = fmaf(p, pw, h.z); row[j+2] = tanhf(a); p = sgnf(a);
        a = fmaf(p, pw, h.w); row[j+3] = tanhf(a); p = sgnf(a);
    }
    for (; j < limit; ++j) {
        const float a = fmaf(p, pw, row[j]);
        row[j] = tanhf(a);
        p = sgnf(a);
    }
}

extern "C" void kernel_launch(void* const* d_in, const int* in_sizes, int n_in,
                              void* d_out, int out_size, void* d_ws, size_t ws_size,
                              hipStream_t stream)
{
    const float* x   = (const float*)d_in[0];
    const float* spv = (const float*)d_in[1];
    const float* w   = (const float*)d_in[2];
    const float* b   = (const float*)d_in[3];
    const float* pw  = (const float*)d_in[4];
    float* out = (float*)d_out;

    // workspace: wT2 64 KiB | trans 512 KiB | entries 128 KiB
    uint8_t* ws = (uint8_t*)d_ws;
    float*    wT2     = (float*)ws;
    uint32_t* trans   = (uint32_t*)(ws + 65536);
    uint8_t*  entries = (uint8_t*)(ws + 65536 + 524288);

    const int conv_blocks = (TY_LEN + TPB - 1) / TPB;   // 4096
    wtrans_kernel<<<64, 256, 0, stream>>>(w, wT2);
    conv_kernel<<<conv_blocks, CBT, 0, stream>>>(x, wT2, b, out);
    scan_pass_a<<<(NM * NCH) / 256, 256, 0, stream>>>(out, spv, pw, trans);
    scan_pass_b<<<NM, 256, 0, stream>>>(trans, entries);
    scan_pass_c<<<(NM * NCH) / 256, 256, 0, stream>>>(out, spv, pw, entries);
}